// Round 7
// baseline (72.910 us; speedup 1.0000x reference)
//
#include <hip/hip_runtime.h>
#include <stdint.h>

#define NFEAT 16
#define NCOLS 969            // 1 bias + 16 deg1 + 136 deg2 + 816 deg3
#define NROWS 65536
#define LSTRIDE 972          // dwords per LDS row: mult of 4 (16B writes), %32=12 (bank spread)
#define PASS_ROWS 16
#define PASSES_PER_BLOCK 8   // 512 blocks * 8 passes * 16 rows = 65536
#define PASS_ELEMS (PASS_ROWS * NCOLS)   // 15504 dwords, flat-contiguous in out

typedef float floatx4 __attribute__((ext_vector_type(4)));

// ---------------------------------------------------------------------------
// Static compute of cols [CBASE, CEND) of one row into LDS. All 969 columns
// emitted in sklearn/jax reference order (verified absmax 0.0 in R1/R3-R6);
// out-of-range emits are compile-time dead. Zero decode, zero gathers.
// ---------------------------------------------------------------------------
template<int CBASE, int CEND>
__device__ __forceinline__ void compute_range(const float* xr, float* ldsrow) {
    float buf[4];
    int col = 0;
#define EMIT(P) do { \
    if (col >= CBASE && col < CEND) { \
        buf[(col - CBASE) & 3] = (P); \
        if (((col - CBASE) & 3) == 3) { \
            floatx4 p; p[0] = buf[0]; p[1] = buf[1]; p[2] = buf[2]; p[3] = buf[3]; \
            *(floatx4*)&ldsrow[col - 3] = p; /* CBASE%4==0 -> 16B-aligned */ \
        } \
    } \
    ++col; } while (0)
    EMIT(1.0f);                                   // bias
    #pragma unroll
    for (int i = 0; i < NFEAT; ++i) EMIT(xr[i]);  // degree 1
    #pragma unroll
    for (int i = 0; i < NFEAT; ++i)               // degree 2
        #pragma unroll
        for (int j = i; j < NFEAT; ++j) EMIT(xr[i] * xr[j]);
    #pragma unroll
    for (int i = 0; i < NFEAT; ++i)               // degree 3 (x_i*x_j reused via CSE)
        #pragma unroll
        for (int j = i; j < NFEAT; ++j)
            #pragma unroll
            for (int k = j; k < NFEAT; ++k) EMIT((xr[i] * xr[j]) * xr[k]);
#undef EMIT
    constexpr int rem = (CEND - CBASE) & 3;       // ragged tail (range 15 only)
    if constexpr (rem != 0) {
        #pragma unroll
        for (int e = 0; e < rem; ++e) ldsrow[CEND - rem + e] = buf[e];
    }
}

__device__ __forceinline__ void compute_dispatch(int range, const float* xr, float* ldsrow) {
    switch (range) {   // uniform per 16-lane group -> 4 serial bodies per wave
        case  0: compute_range<  0,  60>(xr, ldsrow); break;
        case  1: compute_range< 60, 120>(xr, ldsrow); break;
        case  2: compute_range<120, 180>(xr, ldsrow); break;
        case  3: compute_range<180, 240>(xr, ldsrow); break;
        case  4: compute_range<240, 300>(xr, ldsrow); break;
        case  5: compute_range<300, 360>(xr, ldsrow); break;
        case  6: compute_range<360, 420>(xr, ldsrow); break;
        case  7: compute_range<420, 480>(xr, ldsrow); break;
        case  8: compute_range<480, 540>(xr, ldsrow); break;
        case  9: compute_range<540, 600>(xr, ldsrow); break;
        case 10: compute_range<600, 660>(xr, ldsrow); break;
        case 11: compute_range<660, 720>(xr, ldsrow); break;
        case 12: compute_range<720, 780>(xr, ldsrow); break;
        case 13: compute_range<780, 840>(xr, ldsrow); break;
        case 14: compute_range<840, 900>(xr, ldsrow); break;
        case 15: compute_range<900, 969>(xr, ldsrow); break;
    }
}

// Flat contiguous copy LDS -> out for one 16-row pass (15504 dwords).
__device__ __forceinline__ void store_pass(float* __restrict__ out, int rowbase,
                                           int tid, const float* lds) {
    float* dst = out + (size_t)rowbase * NCOLS;
    #pragma unroll 4
    for (int g = tid; g < PASS_ELEMS; g += 256) {
        int r = g / NCOLS;              // constant divisor -> magic multiply
        int c = g - r * NCOLS;
        __builtin_nontemporal_store(lds[r * LSTRIDE + c], dst + g);
    }
}

__global__ void __launch_bounds__(256, 2)
poly_rows(const float* __restrict__ x, float* __restrict__ out) {
    __shared__ float lds[PASS_ROWS * LSTRIDE];   // 62,208 B -> 2 blocks/CU

    const int tid    = threadIdx.x;
    const int rowsel = tid & 15;                 // row within pass
    const int range  = tid >> 4;                 // 0..15, uniform per 16-lane group
    float* ldsrow = &lds[rowsel * LSTRIDE];

    const int base = blockIdx.x * (PASSES_PER_BLOCK * PASS_ROWS);

    // load x-row for pass 0
    const floatx4* xv = (const floatx4*)(x + (size_t)(base + rowsel) * NFEAT);
    floatx4 a0 = xv[0], a1 = xv[1], a2 = xv[2], a3 = xv[3];

    for (int p = 0; p < PASSES_PER_BLOCK; ++p) {
        float xr[NFEAT] = {a0[0],a0[1],a0[2],a0[3], a1[0],a1[1],a1[2],a1[3],
                           a2[0],a2[1],a2[2],a2[3], a3[0],a3[1],a3[2],a3[3]};
        compute_dispatch(range, xr, ldsrow);

        // prefetch next pass's x-row; latency hides under the store phase
        if (p + 1 < PASSES_PER_BLOCK) {
            const floatx4* nv = (const floatx4*)
                (x + (size_t)(base + (p + 1) * PASS_ROWS + rowsel) * NFEAT);
            a0 = nv[0]; a1 = nv[1]; a2 = nv[2]; a3 = nv[3];
        }

        __syncthreads();
        store_pass(out, base + p * PASS_ROWS, tid, lds);
        __syncthreads();
    }
}

extern "C" void kernel_launch(void* const* d_in, const int* in_sizes, int n_in,
                              void* d_out, int out_size, void* d_ws, size_t ws_size,
                              hipStream_t stream) {
    const float* x = (const float*)d_in[0];
    float* out = (float*)d_out;
    // 512 blocks = 2 per CU (LDS-capped), 8 passes of 16 rows each.
    poly_rows<<<512, 256, 0, stream>>>(x, out);
}